// Round 5
// baseline (3387.656 us; speedup 1.0000x reference)
//
#include <hip/hip_runtime.h>
#include <math.h>

#define BB 256
#define SS 512
#define II 128
#define HH 256

#define R_LDS 12        // Whh chunks/wave in LDS      (chunks 0..11)
#define R_REG 4         // Whh chunks/wave in VGPRs    (chunks 12..15)
#define N_PRE 6         // streamed, issued pre-spin   (chunks 16..21)
#define N_POST 10       // streamed, in-phase          (chunks 22..31)
#define WREG_N 20       // gate: Wih16+Whh4 ; attn: Wa 20

typedef unsigned short ushort_t;
typedef unsigned int uint32;

// d_ws bf16 blob element offsets (each a multiple of 8 -> 16B aligned)
#define OFF_WA   0          // 128*384 = 49152   (swizzled, 48 chunks)
#define OFF_BA   49152      // 128
#define OFF_WIH  49280      // 768*128 = 98304   (swizzled, 16 chunks)
#define OFF_BIH  147584     // 768
#define OFF_WHH  148352     // 768*256 = 196608  (swizzled, 32 chunks)
#define OFF_BHH  344960     // 768
#define OFF_WT   345728     // 256
#define OFF_BT   345984     // 1 (padded to 8)
#define OFF_WF   345992     // 256
#define OFF_BF   346248     // 1

__device__ __forceinline__ float b2f(ushort_t u) {
    union { uint32 i; float f; } v; v.i = ((uint32)u) << 16; return v.f;
}
__device__ __forceinline__ float lo2f(uint32 w) {
    union { uint32 i; float f; } v; v.i = w << 16; return v.f;
}
__device__ __forceinline__ float hi2f(uint32 w) {
    union { uint32 i; float f; } v; v.i = w & 0xFFFF0000u; return v.f;
}
__device__ __forceinline__ ushort_t f2b(float f) {
    union { float f; uint32 i; } v; v.f = f;
    uint32 r = (v.i + 0x7FFFu + ((v.i >> 16) & 1u)) >> 16;
    return (ushort_t)r;
}
__device__ __forceinline__ uint32 pack2(float a, float b) {
    return (uint32)f2b(a) | ((uint32)f2b(b) << 16);
}

#if __has_builtin(__builtin_amdgcn_fdot2_f32_bf16)
typedef __bf16 v2bf __attribute__((ext_vector_type(2)));
__device__ __forceinline__ float dot2u(uint32 w, uint32 v, float acc) {
    return __builtin_amdgcn_fdot2_f32_bf16(
        __builtin_bit_cast(v2bf, w), __builtin_bit_cast(v2bf, v), acc, false);
}
#else
__device__ __forceinline__ float dot2u(uint32 w, uint32 v, float acc) {
    acc = fmaf(lo2f(w), lo2f(v), acc);
    return fmaf(hi2f(w), hi2f(v), acc);
}
#endif
__device__ __forceinline__ float dot4(uint4 w, uint4 v, float acc) {
    acc = dot2u(w.x, v.x, acc); acc = dot2u(w.y, v.y, acc);
    acc = dot2u(w.z, v.z, acc); return dot2u(w.w, v.w, acc);
}

// LDS flag sync helpers (DS-scope acquire/release: lgkmcnt-only, keeps
// global loads in flight -- the whole point of dropping __syncthreads)
__device__ __forceinline__ void spin_ge(int* f, int tgt) {
    while (__hip_atomic_load(f, __ATOMIC_ACQUIRE, __HIP_MEMORY_SCOPE_WORKGROUP) < tgt) {}
}
__device__ __forceinline__ void bump(int* f) {
    __hip_atomic_fetch_add(f, 1, __ATOMIC_RELEASE, __HIP_MEMORY_SCOPE_WORKGROUP);
}

__global__ void cvt_f32_bf16(const float* __restrict__ src, ushort_t* __restrict__ dst, int n) {
    int i = blockIdx.x * 256 + threadIdx.x;
    if (i < n) dst[i] = f2b(src[i]);
}

// Swizzled fp32 -> bf16: uint4 index = ((row/64)*chunks + c)*64 + (row%64)
__global__ void cvt_swz(const float* __restrict__ src, ushort_t* __restrict__ dst,
                        int rows, int chunks) {
    int t = blockIdx.x * 256 + threadIdx.x;
    if (t >= rows * chunks) return;
    int row = t / chunks, c = t % chunks;
    const float* s = src + (size_t)row * chunks * 8 + c * 8;
    uint4 v;
    v.x = pack2(s[0], s[1]); v.y = pack2(s[2], s[3]);
    v.z = pack2(s[4], s[5]); v.w = pack2(s[6], s[7]);
    ((uint4*)dst)[((size_t)(row >> 6) * chunks + c) * 64 + (row & 63)] = v;
}

// One block (1024 threads) per batch row; no __syncthreads in the main loop.
// Waves 0-11 gate (row tid of Wih reg-resident + Whh 12 LDS / 4 reg / 16 stream).
// Waves 12-15 attn (Wa 20 reg-resident + 4 streamed). Waves 0-3 also h-update.
__global__ __launch_bounds__(1024, 4) void da_rnn_kernel(
    const float* __restrict__ x,          // fp32 [B,S,I]
    const ushort_t* __restrict__ wsb,     // bf16 blob in d_ws
    float* __restrict__ out)              // fp32 [B,1]
{
    const int b    = blockIdx.x;
    const int tid  = threadIdx.x;
    const int lane = tid & 63;
    const int wv   = tid >> 6;
    const bool is_gate = (tid < 3 * HH);

    __shared__ __align__(16) uint32 whh_lds[12 * R_LDS * 256]; // 144 KB
    __shared__ __align__(16) uint32 s_xh_p[192];   // packed bf16 [x_t(128); h(256)]
    __shared__ __align__(16) uint32 sxw_p[64];     // packed bf16 alpha*x_t
    __shared__ __align__(16) float  sred[256];
    __shared__ __align__(16) float  sgi[3 * HH];
    __shared__ __align__(16) float  sgh[3 * HH];
    __shared__ __align__(16) float  sx[2][II];     // x_t fp32 double buffer
    __shared__ float swave[4];
    __shared__ int flag_red, flag_xw, flag_xp, flag_gates, flag_h;

    if (tid == 0) { flag_red = 0; flag_xw = 0; flag_xp = 0; flag_gates = 0; flag_h = 0; }
    if (tid < II) s_xh_p[64 + tid] = 0u;           // h_0 = 0 (packed)

    // ---- role-overlaid register-resident weights ----
    uint4 wreg[WREG_N];
    const int a   = tid - 3 * HH;                  // attn index 0..255
    const int row = a & 127;
    const int s   = a >> 7;
    const uint4* whh_base = (const uint4*)(wsb + OFF_WHH) + (size_t)wv * 32 * 64 + lane;
    const uint4* wa_st = nullptr;
    float bias_i = 0.f, bias_h = 0.f, ba_a = 0.f, ba_b = 0.f;

    if (is_gate) {
        const uint4* wih_g = (const uint4*)(wsb + OFF_WIH) + (size_t)wv * 16 * 64 + lane;
        #pragma unroll
        for (int c = 0; c < 16; ++c) wreg[c] = wih_g[c * 64];
        #pragma unroll
        for (int i = 0; i < R_REG; ++i) wreg[16 + i] = whh_base[(R_LDS + i) * 64];
        bias_i = b2f(wsb[OFF_BIH + tid]);
        bias_h = b2f(wsb[OFF_BHH + tid]);
        #pragma unroll
        for (int c = 0; c < R_LDS; ++c)
            ((uint4*)whh_lds)[(wv * R_LDS + c) * 64 + lane] = whh_base[c * 64];
    } else {
        const uint4* wa_g = (const uint4*)(wsb + OFF_WA);
        const size_t gbase = ((size_t)(row >> 6) * 48 + s * 24) * 64 + (row & 63);
        #pragma unroll
        for (int i = 0; i < WREG_N; ++i) wreg[i] = wa_g[gbase + (size_t)i * 64];
        wa_st = wa_g + gbase + (size_t)WREG_N * 64;  // streamed chunks 20..23
        ba_a = b2f(wsb[OFF_BA + lane]);
        ba_b = b2f(wsb[OFF_BA + 64 + lane]);
    }

    float h_reg = 0.f, c_reg = 0.f, m_run = -2.0f, l_run = 0.f;
    float wt_j = 0.f, wf_j = 0.f, bt_r = 0.f;
    if (tid < HH) {
        wt_j = b2f(wsb[OFF_WT + tid]);
        wf_j = b2f(wsb[OFF_WF + tid]);
        bt_r = b2f(wsb[OFF_BT]);
    }

    const float* xrow = x + (size_t)b * SS * II;
    if (!is_gate && a >= 64 && a < 192) {          // x_0 load + pack
        const int idx = a - 64;
        float v = xrow[idx];
        sx[0][idx] = v;
        float vn = __shfl_down(v, 1);
        if (!(idx & 1)) s_xh_p[idx >> 1] = pack2(v, vn);
    }
    __syncthreads();                               // single prologue barrier

    const uint4* st4 = (const uint4*)s_xh_p;       // 48 chunks of [x;h]
    const uint4* shp = (const uint4*)s_xh_p + 16;  // 32 chunks of h
    const uint4* xwp = (const uint4*)sxw_p;        // 16 chunks of xw
    const uint4* whl = (const uint4*)whh_lds + (size_t)(wv * R_LDS) * 64 + lane;

    for (int t = 0; t < SS; ++t) {
        const int p = t & 1;

        if (is_gate) {
            // pre-spin stream issue (h-independent): overlaps previous tail
            uint4 sbuf[N_PRE];
            #pragma unroll
            for (int i = 0; i < N_PRE; ++i)
                sbuf[i] = whh_base[(R_LDS + R_REG + i) * 64];

            spin_ge(&flag_h, 4 * t);               // h_t ready

            float gh = bias_h;
            #pragma unroll
            for (int c = 0; c < R_LDS; ++c) gh = dot4(whl[c * 64], shp[c], gh);
            #pragma unroll
            for (int i = 0; i < R_REG; ++i) gh = dot4(wreg[16 + i], shp[R_LDS + i], gh);
            #pragma unroll
            for (int i = 0; i < N_PRE; ++i)
                gh = dot4(sbuf[i], shp[R_LDS + R_REG + i], gh);
            #pragma unroll 4
            for (int i = 0; i < N_POST; ++i)
                gh = dot4(whh_base[(R_LDS + R_REG + N_PRE + i) * 64],
                          shp[R_LDS + R_REG + N_PRE + i], gh);
            sgh[tid] = gh;

            spin_ge(&flag_xw, t + 1);              // xw ready
            float gi = bias_i;
            #pragma unroll
            for (int c = 0; c < 16; ++c) gi = dot4(wreg[c], xwp[c], gi);
            sgi[tid] = gi;
            if (lane == 0) bump(&flag_gates);

            if (tid < HH) {
                // ---- h update (waves 0-3) ----
                spin_ge(&flag_gates, 12 * (t + 1));
                const float r = 1.f / (1.f + expf(-(sgi[tid] + sgh[tid])));
                const float z = 1.f / (1.f + expf(-(sgi[tid + HH] + sgh[tid + HH])));
                const float n = tanhf(sgi[tid + 2 * HH] + r * sgh[tid + 2 * HH]);
                h_reg = (1.f - z) * n + z * h_reg;
                float hn2 = __shfl_down(h_reg, 1);
                if (!(tid & 1)) s_xh_p[64 + (tid >> 1)] = pack2(h_reg, hn2);
                float pd = wt_j * h_reg;
                for (int off = 32; off; off >>= 1) pd += __shfl_down(pd, off);
                if (lane == 0) swave[wv] = pd;
                if (lane == 0) bump(&flag_h);
                spin_ge(&flag_h, 4 * (t + 1));
                // redundant per-thread online softmax over time
                float dot = swave[0] + swave[1] + swave[2] + swave[3] + bt_r;
                float st = tanhf(dot);
                float mn = fmaxf(m_run, st);
                float aa = expf(m_run - mn), ww = expf(st - mn);
                l_run = l_run * aa + ww;
                m_run = mn;
                c_reg = c_reg * aa + ww * h_reg;
            }
        } else {
            // pre-spin issue of streamed Wa chunks (h/x-independent)
            uint4 abuf[4];
            #pragma unroll
            for (int i = 0; i < 4; ++i) abuf[i] = wa_st[i * 64];

            spin_ge(&flag_h, 4 * t);               // h_t ready
            spin_ge(&flag_xp, 2 * t);              // x_t ready

            float acc = 0.f;
            #pragma unroll
            for (int i = 0; i < WREG_N; ++i) acc = dot4(wreg[i], st4[s * 24 + i], acc);
            #pragma unroll
            for (int i = 0; i < 4; ++i) acc = dot4(abuf[i], st4[s * 24 + WREG_N + i], acc);
            sred[a] = acc;
            if (lane == 0) bump(&flag_red);
            spin_ge(&flag_red, 4 * (t + 1));

            if (a < 64) {
                // wave 12: combine + tanh + softmax + packed xw
                float s_a = sred[lane] + sred[128 + lane] + ba_a;
                float s_b = sred[64 + lane] + sred[192 + lane] + ba_b;
                s_a = tanhf(s_a); s_b = tanhf(s_b);
                float m = fmaxf(s_a, s_b);
                for (int off = 32; off; off >>= 1) m = fmaxf(m, __shfl_xor(m, off));
                float e_a = expf(s_a - m), e_b = expf(s_b - m);
                float sum = e_a + e_b;
                for (int off = 32; off; off >>= 1) sum += __shfl_xor(sum, off);
                float inv = 1.f / sum;
                float xa = e_a * inv * sx[p][lane];
                float xb = e_b * inv * sx[p][64 + lane];
                float xa1 = __shfl_down(xa, 1), xb1 = __shfl_down(xb, 1);
                if (!(lane & 1)) {
                    sxw_p[lane >> 1]        = pack2(xa, xa1);
                    sxw_p[32 + (lane >> 1)] = pack2(xb, xb1);
                }
                if (lane == 0)
                    __hip_atomic_store(&flag_xw, t + 1, __ATOMIC_RELEASE,
                                       __HIP_MEMORY_SCOPE_WORKGROUP);
            } else if (a < 192) {
                // waves 13-14: prefetch x_{t+1}; safe vs readers via flag_red
                if (t + 1 < SS) {
                    const int idx = a - 64;
                    float v = xrow[(t + 1) * II + idx];
                    sx[p ^ 1][idx] = v;
                    float vn = __shfl_down(v, 1);
                    if (!(idx & 1)) s_xh_p[idx >> 1] = pack2(v, vn);
                }
                if (lane == 0) bump(&flag_xp);
            }
        }
    }

    // ---- epilogue ----
    __syncthreads();
    if (tid < HH) {
        float ctx = c_reg / l_run;
        float pd = wf_j * ctx;
        for (int off = 32; off; off >>= 1) pd += __shfl_down(pd, off);
        if (lane == 0) swave[wv] = pd;
    }
    __syncthreads();
    if (tid == 0) {
        float logit = swave[0] + swave[1] + swave[2] + swave[3] + b2f(wsb[OFF_BF]);
        out[b] = 1.f / (1.f + expf(-logit));
    }
}

extern "C" void kernel_launch(void* const* d_in, const int* in_sizes, int n_in,
                              void* d_out, int out_size, void* d_ws, size_t ws_size,
                              hipStream_t stream) {
    ushort_t* wsb = (ushort_t*)d_ws;

    cvt_swz<<<dim3((128 * 48 + 255) / 256), dim3(256), 0, stream>>>(
        (const float*)d_in[1], wsb + OFF_WA, 128, 48);           // W_a  [128,384]
    cvt_swz<<<dim3((768 * 16 + 255) / 256), dim3(256), 0, stream>>>(
        (const float*)d_in[3], wsb + OFF_WIH, 768, 16);          // W_ih [768,128]
    cvt_swz<<<dim3((768 * 32 + 255) / 256), dim3(256), 0, stream>>>(
        (const float*)d_in[5], wsb + OFF_WHH, 768, 32);          // W_hh [768,256]

    struct { int src_idx; int off; int n; } cv[7] = {
        {2, OFF_BA,  II}, {4, OFF_BIH, 3 * HH}, {6, OFF_BHH, 3 * HH},
        {7, OFF_WT,  HH}, {8, OFF_BT, 1}, {9, OFF_WF, HH}, {10, OFF_BF, 1},
    };
    for (int i = 0; i < 7; ++i) {
        int blocks = (cv[i].n + 255) / 256;
        cvt_f32_bf16<<<dim3(blocks), dim3(256), 0, stream>>>(
            (const float*)d_in[cv[i].src_idx], wsb + cv[i].off, cv[i].n);
    }

    da_rnn_kernel<<<dim3(BB), dim3(1024), 0, stream>>>(
        (const float*)d_in[0], wsb, (float*)d_out);
}

// Round 6
// 2796.327 us; speedup vs baseline: 1.2115x; 1.2115x over previous
//
#include <hip/hip_runtime.h>
#include <math.h>

#define BB 256
#define SS 512
#define II 128
#define HH 256

#define R_LDS 12        // Whh chunks/wave in LDS    (chunks 0..11)
#define N_PRE 4         // streamed, issued pre-spin (chunks 12..15)
#define N_POST 16       // streamed, in-phase        (chunks 16..31)
#define WREG_N 16       // gate: Wih 16 ; attn: Wa 16  (proven no-spill size)

typedef unsigned short ushort_t;
typedef unsigned int uint32;

// d_ws bf16 blob element offsets (each a multiple of 8 -> 16B aligned)
#define OFF_WA   0          // 128*384 = 49152   (swizzled, 48 chunks)
#define OFF_BA   49152      // 128
#define OFF_WIH  49280      // 768*128 = 98304   (swizzled, 16 chunks)
#define OFF_BIH  147584     // 768
#define OFF_WHH  148352     // 768*256 = 196608  (swizzled, 32 chunks)
#define OFF_BHH  344960     // 768
#define OFF_WT   345728     // 256
#define OFF_BT   345984     // 1 (padded to 8)
#define OFF_WF   345992     // 256
#define OFF_BF   346248     // 1

__device__ __forceinline__ float b2f(ushort_t u) {
    union { uint32 i; float f; } v; v.i = ((uint32)u) << 16; return v.f;
}
__device__ __forceinline__ float lo2f(uint32 w) {
    union { uint32 i; float f; } v; v.i = w << 16; return v.f;
}
__device__ __forceinline__ float hi2f(uint32 w) {
    union { uint32 i; float f; } v; v.i = w & 0xFFFF0000u; return v.f;
}
__device__ __forceinline__ ushort_t f2b(float f) {
    union { float f; uint32 i; } v; v.f = f;
    uint32 r = (v.i + 0x7FFFu + ((v.i >> 16) & 1u)) >> 16;
    return (ushort_t)r;
}
__device__ __forceinline__ uint32 pack2(float a, float b) {
    return (uint32)f2b(a) | ((uint32)f2b(b) << 16);
}

#if __has_builtin(__builtin_amdgcn_fdot2_f32_bf16)
typedef __bf16 v2bf __attribute__((ext_vector_type(2)));
__device__ __forceinline__ float dot2u(uint32 w, uint32 v, float acc) {
    return __builtin_amdgcn_fdot2_f32_bf16(
        __builtin_bit_cast(v2bf, w), __builtin_bit_cast(v2bf, v), acc, false);
}
#else
__device__ __forceinline__ float dot2u(uint32 w, uint32 v, float acc) {
    acc = fmaf(lo2f(w), lo2f(v), acc);
    return fmaf(hi2f(w), hi2f(v), acc);
}
#endif
__device__ __forceinline__ float dot4(uint4 w, uint4 v, float acc) {
    acc = dot2u(w.x, v.x, acc); acc = dot2u(w.y, v.y, acc);
    acc = dot2u(w.z, v.z, acc); return dot2u(w.w, v.w, acc);
}

// LDS flag sync (DS-scope acquire/release: lgkmcnt-only, global loads stay
// in flight across sync points)
__device__ __forceinline__ void spin_ge(int* f, int tgt) {
    while (__hip_atomic_load(f, __ATOMIC_ACQUIRE, __HIP_MEMORY_SCOPE_WORKGROUP) < tgt) {}
}
__device__ __forceinline__ void bump(int* f) {
    __hip_atomic_fetch_add(f, 1, __ATOMIC_RELEASE, __HIP_MEMORY_SCOPE_WORKGROUP);
}

__global__ void cvt_f32_bf16(const float* __restrict__ src, ushort_t* __restrict__ dst, int n) {
    int i = blockIdx.x * 256 + threadIdx.x;
    if (i < n) dst[i] = f2b(src[i]);
}

// Swizzled fp32 -> bf16: uint4 index = ((row/64)*chunks + c)*64 + (row%64)
__global__ void cvt_swz(const float* __restrict__ src, ushort_t* __restrict__ dst,
                        int rows, int chunks) {
    int t = blockIdx.x * 256 + threadIdx.x;
    if (t >= rows * chunks) return;
    int row = t / chunks, c = t % chunks;
    const float* s = src + (size_t)row * chunks * 8 + c * 8;
    uint4 v;
    v.x = pack2(s[0], s[1]); v.y = pack2(s[2], s[3]);
    v.z = pack2(s[4], s[5]); v.w = pack2(s[6], s[7]);
    ((uint4*)dst)[((size_t)(row >> 6) * chunks + c) * 64 + (row & 63)] = v;
}

// One block (1024 threads) per batch row; no __syncthreads in the main loop.
// Waves 0-11 gate: row tid of Wih (16 chunks reg) + Whh (12 LDS / 20 stream).
// Waves 12-15 attn: Wa 16 reg + 8 streamed. Waves 0-3 also do the h-update.
__global__ __launch_bounds__(1024, 4) void da_rnn_kernel(
    const float* __restrict__ x,          // fp32 [B,S,I]
    const ushort_t* __restrict__ wsb,     // bf16 blob in d_ws
    float* __restrict__ out)              // fp32 [B,1]
{
    const int b    = blockIdx.x;
    const int tid  = threadIdx.x;
    const int lane = tid & 63;
    const int wv   = tid >> 6;
    const bool is_gate = (tid < 3 * HH);

    __shared__ __align__(16) uint32 whh_lds[12 * R_LDS * 256]; // 144 KB
    __shared__ __align__(16) uint32 s_xh_p[192];   // packed bf16 [x_t(128); h(256)]
    __shared__ __align__(16) uint32 sxw_p[64];     // packed bf16 alpha*x_t
    __shared__ __align__(16) float  sred[256];
    __shared__ __align__(16) float  sgi[3 * HH];
    __shared__ __align__(16) float  sgh[3 * HH];
    __shared__ __align__(16) float  sx[2][II];     // x_t fp32 double buffer
    __shared__ float swave[4];
    __shared__ int flag_red, flag_xw, flag_xp, flag_gates, flag_h;

    if (tid == 0) { flag_red = 0; flag_xw = 0; flag_xp = 0; flag_gates = 0; flag_h = 0; }
    if (tid < II) s_xh_p[64 + tid] = 0u;           // h_0 = 0 (packed)

    // ---- role-overlaid register-resident weights (64 VGPRs, proven safe) ----
    uint4 wreg[WREG_N];
    const int a   = tid - 3 * HH;                  // attn index 0..255
    const int row = a & 127;
    const int s   = a >> 7;
    const uint4* whh_base = (const uint4*)(wsb + OFF_WHH) + (size_t)wv * 32 * 64 + lane;
    const uint4* wa_st = nullptr;
    float bias_i = 0.f, bias_h = 0.f, ba_a = 0.f, ba_b = 0.f;

    if (is_gate) {
        const uint4* wih_g = (const uint4*)(wsb + OFF_WIH) + (size_t)wv * 16 * 64 + lane;
        #pragma unroll
        for (int c = 0; c < 16; ++c) wreg[c] = wih_g[c * 64];
        bias_i = b2f(wsb[OFF_BIH + tid]);
        bias_h = b2f(wsb[OFF_BHH + tid]);
        #pragma unroll
        for (int c = 0; c < R_LDS; ++c)
            ((uint4*)whh_lds)[(wv * R_LDS + c) * 64 + lane] = whh_base[c * 64];
    } else {
        const uint4* wa_g = (const uint4*)(wsb + OFF_WA);
        const size_t gbase = ((size_t)(row >> 6) * 48 + s * 24) * 64 + (row & 63);
        #pragma unroll
        for (int i = 0; i < WREG_N; ++i) wreg[i] = wa_g[gbase + (size_t)i * 64];
        wa_st = wa_g + gbase + (size_t)WREG_N * 64;  // streamed chunks 16..23
        ba_a = b2f(wsb[OFF_BA + lane]);
        ba_b = b2f(wsb[OFF_BA + 64 + lane]);
    }

    float h_reg = 0.f, c_reg = 0.f, m_run = -2.0f, l_run = 0.f;
    float wt_j = 0.f, wf_j = 0.f, bt_r = 0.f;
    if (tid < HH) {
        wt_j = b2f(wsb[OFF_WT + tid]);
        wf_j = b2f(wsb[OFF_WF + tid]);
        bt_r = b2f(wsb[OFF_BT]);
    }

    const float* xrow = x + (size_t)b * SS * II;
    if (!is_gate && a >= 64 && a < 192) {          // x_0 load + pack
        const int idx = a - 64;
        float v = xrow[idx];
        sx[0][idx] = v;
        float vn = __shfl_down(v, 1);
        if (!(idx & 1)) s_xh_p[idx >> 1] = pack2(v, vn);
    }
    __syncthreads();                               // single prologue barrier

    const uint4* st4 = (const uint4*)s_xh_p;       // 48 chunks of [x;h]
    const uint4* shp = (const uint4*)s_xh_p + 16;  // 32 chunks of h
    const uint4* xwp = (const uint4*)sxw_p;        // 16 chunks of xw
    const uint4* whl = (const uint4*)whh_lds + (size_t)(wv * R_LDS) * 64 + lane;

    for (int t = 0; t < SS; ++t) {
        const int p = t & 1;

        if (is_gate) {
            // pre-spin stream issue (h-independent): flies during prev tail
            uint4 sbuf[N_PRE];
            #pragma unroll
            for (int i = 0; i < N_PRE; ++i)
                sbuf[i] = whh_base[(R_LDS + i) * 64];

            spin_ge(&flag_h, 4 * t);               // h_t ready

            float gh = bias_h;
            #pragma unroll
            for (int c = 0; c < R_LDS; ++c) gh = dot4(whl[c * 64], shp[c], gh);
            #pragma unroll
            for (int i = 0; i < N_PRE; ++i)
                gh = dot4(sbuf[i], shp[R_LDS + i], gh);
            #pragma unroll 4
            for (int i = 0; i < N_POST; ++i)
                gh = dot4(whh_base[(R_LDS + N_PRE + i) * 64],
                          shp[R_LDS + N_PRE + i], gh);
            sgh[tid] = gh;

            spin_ge(&flag_xw, t + 1);              // xw ready
            float gi = bias_i;
            #pragma unroll
            for (int c = 0; c < 16; ++c) gi = dot4(wreg[c], xwp[c], gi);
            sgi[tid] = gi;
            if (lane == 0) bump(&flag_gates);

            if (tid < HH) {
                // ---- h update (waves 0-3) ----
                spin_ge(&flag_gates, 12 * (t + 1));
                const float r = 1.f / (1.f + expf(-(sgi[tid] + sgh[tid])));
                const float z = 1.f / (1.f + expf(-(sgi[tid + HH] + sgh[tid + HH])));
                const float n = tanhf(sgi[tid + 2 * HH] + r * sgh[tid + 2 * HH]);
                h_reg = (1.f - z) * n + z * h_reg;
                float hn2 = __shfl_down(h_reg, 1);
                if (!(tid & 1)) s_xh_p[64 + (tid >> 1)] = pack2(h_reg, hn2);
                float pd = wt_j * h_reg;
                for (int off = 32; off; off >>= 1) pd += __shfl_down(pd, off);
                if (lane == 0) swave[wv] = pd;
                if (lane == 0) bump(&flag_h);
                spin_ge(&flag_h, 4 * (t + 1));
                // redundant per-thread online softmax over time
                float dot = swave[0] + swave[1] + swave[2] + swave[3] + bt_r;
                float st = tanhf(dot);
                float mn = fmaxf(m_run, st);
                float aa = expf(m_run - mn), ww = expf(st - mn);
                l_run = l_run * aa + ww;
                m_run = mn;
                c_reg = c_reg * aa + ww * h_reg;
            }
        } else {
            // pre-spin issue of streamed Wa chunks 16..19
            uint4 abuf[4];
            #pragma unroll
            for (int i = 0; i < 4; ++i) abuf[i] = wa_st[i * 64];

            spin_ge(&flag_h, 4 * t);               // h_t ready
            spin_ge(&flag_xp, 2 * t);              // x_t ready

            float acc = 0.f;
            #pragma unroll
            for (int i = 0; i < WREG_N; ++i) acc = dot4(wreg[i], st4[s * 24 + i], acc);
            #pragma unroll
            for (int i = 0; i < 4; ++i) acc = dot4(abuf[i], st4[s * 24 + 16 + i], acc);
            #pragma unroll
            for (int i = 0; i < 4; ++i) acc = dot4(wa_st[(4 + i) * 64], st4[s * 24 + 20 + i], acc);
            sred[a] = acc;
            if (lane == 0) bump(&flag_red);
            spin_ge(&flag_red, 4 * (t + 1));

            if (a < 64) {
                // wave 12: combine + tanh + softmax + packed xw
                float s_a = sred[lane] + sred[128 + lane] + ba_a;
                float s_b = sred[64 + lane] + sred[192 + lane] + ba_b;
                s_a = tanhf(s_a); s_b = tanhf(s_b);
                float m = fmaxf(s_a, s_b);
                for (int off = 32; off; off >>= 1) m = fmaxf(m, __shfl_xor(m, off));
                float e_a = expf(s_a - m), e_b = expf(s_b - m);
                float sum = e_a + e_b;
                for (int off = 32; off; off >>= 1) sum += __shfl_xor(sum, off);
                float inv = 1.f / sum;
                float xa = e_a * inv * sx[p][lane];
                float xb = e_b * inv * sx[p][64 + lane];
                float xa1 = __shfl_down(xa, 1), xb1 = __shfl_down(xb, 1);
                if (!(lane & 1)) {
                    sxw_p[lane >> 1]        = pack2(xa, xa1);
                    sxw_p[32 + (lane >> 1)] = pack2(xb, xb1);
                }
                if (lane == 0)
                    __hip_atomic_store(&flag_xw, t + 1, __ATOMIC_RELEASE,
                                       __HIP_MEMORY_SCOPE_WORKGROUP);
            } else if (a < 192) {
                // waves 13-14: prefetch x_{t+1}; safe vs readers via flag_red
                if (t + 1 < SS) {
                    const int idx = a - 64;
                    float v = xrow[(t + 1) * II + idx];
                    sx[p ^ 1][idx] = v;
                    float vn = __shfl_down(v, 1);
                    if (!(idx & 1)) s_xh_p[idx >> 1] = pack2(v, vn);
                }
                if (lane == 0) bump(&flag_xp);
            }
        }
    }

    // ---- epilogue ----
    __syncthreads();
    if (tid < HH) {
        float ctx = c_reg / l_run;
        float pd = wf_j * ctx;
        for (int off = 32; off; off >>= 1) pd += __shfl_down(pd, off);
        if (lane == 0) swave[wv] = pd;
    }
    __syncthreads();
    if (tid == 0) {
        float logit = swave[0] + swave[1] + swave[2] + swave[3] + b2f(wsb[OFF_BF]);
        out[b] = 1.f / (1.f + expf(-logit));
    }
}

extern "C" void kernel_launch(void* const* d_in, const int* in_sizes, int n_in,
                              void* d_out, int out_size, void* d_ws, size_t ws_size,
                              hipStream_t stream) {
    ushort_t* wsb = (ushort_t*)d_ws;

    cvt_swz<<<dim3((128 * 48 + 255) / 256), dim3(256), 0, stream>>>(
        (const float*)d_in[1], wsb + OFF_WA, 128, 48);           // W_a  [128,384]
    cvt_swz<<<dim3((768 * 16 + 255) / 256), dim3(256), 0, stream>>>(
        (const float*)d_in[3], wsb + OFF_WIH, 768, 16);          // W_ih [768,128]
    cvt_swz<<<dim3((768 * 32 + 255) / 256), dim3(256), 0, stream>>>(
        (const float*)d_in[5], wsb + OFF_WHH, 768, 32);          // W_hh [768,256]

    struct { int src_idx; int off; int n; } cv[7] = {
        {2, OFF_BA,  II}, {4, OFF_BIH, 3 * HH}, {6, OFF_BHH, 3 * HH},
        {7, OFF_WT,  HH}, {8, OFF_BT, 1}, {9, OFF_WF, HH}, {10, OFF_BF, 1},
    };
    for (int i = 0; i < 7; ++i) {
        int blocks = (cv[i].n + 255) / 256;
        cvt_f32_bf16<<<dim3(blocks), dim3(256), 0, stream>>>(
            (const float*)d_in[cv[i].src_idx], wsb + cv[i].off, cv[i].n);
    }

    da_rnn_kernel<<<dim3(BB), dim3(1024), 0, stream>>>(
        (const float*)d_in[0], wsb, (float*)d_out);
}